// Round 3
// 257.960 us; speedup vs baseline: 1.0119x; 1.0119x over previous
//
#include <hip/hip_runtime.h>
#include <math.h>

#define ALPHA 0.12f
#define BETA  0.88f
#define OMEGA 6.0f
#define TWO_PI 6.28318530717958647692f

constexpr int Bn   = 4;
constexpr int Tn   = 4096;
constexpr int Dn   = 2048;
constexpr int HALF = Dn / 2;      // 1024
constexpr int L    = 64;          // chunk length
constexpr int NC   = Tn / L;      // 64 chunks

typedef float fx4 __attribute__((ext_vector_type(4)));

constexpr float beta_pow(int n) {
    float r = 1.0f;
    for (int i = 0; i < n; ++i) r *= BETA;
    return r;
}
constexpr float BETA_L = beta_pow(L);

// ---------------------------------------------------------------------------
// Kernel 1: blocks [0,512): per-chunk local scan endpoint (zero init).
//   S[b, c, d] = sum_{i=0..L-1} BETA^(L-1-i) * u[b, c*L+i, d]
//   One thread per (b, c, d4). 131072 threads.
// Blocks [512,528): theta cos/sin table (independent work, runs concurrently).
// ---------------------------------------------------------------------------
__global__ void k_chunksum(const float* __restrict__ x,
                           const float* __restrict__ input_scale,
                           float* __restrict__ S,
                           float* __restrict__ ctab, float* __restrict__ stab,
                           const int* __restrict__ step_idx) {
    if (blockIdx.x >= 512) {
        int t = (blockIdx.x - 512) * blockDim.x + threadIdx.x;  // 0..4095
        float tg = (float)(t + 1 + *step_idx);
        float theta = fmodf(OMEGA * log1pf(tg), TWO_PI);
        ctab[t] = cosf(theta);
        stab[t] = sinf(theta);
        return;
    }
    int gid = blockIdx.x * blockDim.x + threadIdx.x;
    int d4 = gid & (Dn / 4 - 1);          // 0..511
    int c  = (gid >> 9) & (NC - 1);       // 0..63
    int b  = gid >> 15;                   // 0..3
    const float sc = ALPHA * (*input_scale);

    const fx4* xp = (const fx4*)(x + ((size_t)b * Tn + (size_t)c * L) * Dn) + d4;
    fx4 m = (fx4)(0.0f);
#pragma unroll 8
    for (int i = 0; i < L; ++i) {
        fx4 v = xp[(size_t)i * (Dn / 4)];
        m = BETA * m + sc * v;
    }
    ((fx4*)S)[gid] = m;   // gid*4 == b*NC*Dn + c*Dn + d4*4
}

// ---------------------------------------------------------------------------
// Kernel 2: final pass. One block per (b, c); thread per pair-fx4 p4.
//  Prologue: block computes its own carry-in E_{c-1} by scanning the c
//  chunk sums S[b, 0..c-1, :] (L2/L3-hit, coalesced, avg 32 iters) —
//  identical arithmetic order to the old k_mid, so results are bit-equal.
//  Then re-run exact sequential recurrence from the carry-in, rotate,
//  add residual. ctab/stab reads are wave-uniform broadcast L2 hits
//  (same pattern as the known-good baseline k_final; no LDS, no barrier).
//  x re-read hits Infinity Cache (134 MB < 256 MiB). Nontemporal stores.
// ---------------------------------------------------------------------------
__global__ void k_final(const float* __restrict__ x,
                        const float* __restrict__ gate,
                        const float* __restrict__ input_scale,
                        const float* __restrict__ ctab,
                        const float* __restrict__ stab,
                        const float* __restrict__ S,
                        const float* __restrict__ mem_state,
                        float* __restrict__ out) {
    int p4 = threadIdx.x;                 // 0..255
    int c  = blockIdx.x & (NC - 1);       // 0..63
    int b  = blockIdx.x >> 6;             // 0..3

    const float sc  = ALPHA * (*input_scale);
    const float sig = 1.0f / (1.0f + expf(-(*gate)));

    // carry-in scan: ma/mb = E_{c-1} for this block's chunk
    fx4 ma = ((const fx4*)mem_state)[p4];
    fx4 mb = ((const fx4*)mem_state)[p4 + HALF / 4];
    const fx4* Sa = (const fx4*)(S + (size_t)b * NC * Dn) + p4;
    const fx4* Sb = (const fx4*)(S + (size_t)b * NC * Dn + HALF) + p4;
#pragma unroll 4
    for (int j = 0; j < c; ++j) {
        ma = BETA_L * ma + Sa[(size_t)j * (Dn / 4)];
        mb = BETA_L * mb + Sb[(size_t)j * (Dn / 4)];
    }

    size_t base = ((size_t)b * Tn + (size_t)c * L) * Dn;
    const fx4* xa = (const fx4*)(x + base) + p4;
    const fx4* xb = (const fx4*)(x + base + HALF) + p4;
    fx4* oa = (fx4*)(out + base) + p4;
    fx4* ob = (fx4*)(out + base + HALF) + p4;

    int t0 = c * L;
#pragma unroll 4
    for (int i = 0; i < L; ++i) {
        fx4 va = xa[(size_t)i * (Dn / 4)];
        fx4 vb = xb[(size_t)i * (Dn / 4)];
        ma = BETA * ma + sc * va;
        mb = BETA * mb + sc * vb;
        float cth = ctab[t0 + i];
        float sth = stab[t0 + i];
        fx4 ra = va + sig * (ma * cth - mb * sth);
        fx4 rb = vb + sig * (ma * sth + mb * cth);
        __builtin_nontemporal_store(ra, &oa[(size_t)i * (Dn / 4)]);
        __builtin_nontemporal_store(rb, &ob[(size_t)i * (Dn / 4)]);
    }
}

// ---------------------------------------------------------------------------
extern "C" void kernel_launch(void* const* d_in, const int* in_sizes, int n_in,
                              void* d_out, int out_size, void* d_ws, size_t ws_size,
                              hipStream_t stream) {
    const float* x           = (const float*)d_in[0];
    const float* gate        = (const float*)d_in[1];
    const float* input_scale = (const float*)d_in[2];
    const float* mem_state   = (const float*)d_in[3];
    const int*   step_idx    = (const int*)d_in[4];
    float* out = (float*)d_out;

    float* ws   = (float*)d_ws;
    float* ctab = ws;             // Tn floats
    float* stab = ws + Tn;        // Tn floats
    float* SC   = ws + 2 * Tn;    // Bn*NC*Dn floats (2 MiB)

    k_chunksum<<<512 + Tn / 256, 256, 0, stream>>>(x, input_scale, SC,
                                                   ctab, stab, step_idx);
    k_final<<<Bn * NC, 256, 0, stream>>>(x, gate, input_scale, ctab, stab,
                                         SC, mem_state, out);
}